// Round 4
// baseline (750.937 us; speedup 1.0000x reference)
//
#include <hip/hip_runtime.h>
#include <math.h>

#define BATCH 8
#define CCH 256
#define HW 40000
#define HW2 (HW / 2)          // 20000 float2 pixel-pairs per image
#define KSEL 8000
#define EPS_LN 1e-6f
#define EPS_COS 1e-8f
#define CAP 16384             // LDS compaction capacity for threshold-bin members

// ---- workspace layout (uint/float units) ----
// [0)        keys     : BATCH*HW uint (mono keys of score)
// [320000)   contrib  : BATCH*HW floats
// [640000)   hist1    : BATCH*65536 uint
// [1164288)  bsums    : 8 float
#define OFF_KEYS    0
#define OFF_CONTRIB 320000
#define OFF_HIST1   640000
#define OFF_BSUMS   1164288

typedef float v2f __attribute__((ext_vector_type(2)));

__device__ __forceinline__ unsigned int mono_key(float x) {
  unsigned int u = __float_as_uint(x);
  return (u & 0x80000000u) ? ~u : (u | 0x80000000u);
}

// Zero hist1 (+ bsums). 524288 uints.
__global__ __launch_bounds__(256) void zero_kernel(unsigned int* __restrict__ ws) {
  const int n4 = (BATCH * 65536) / 4;
  uint4* p = (uint4*)(ws + OFF_HIST1);
  uint4 z = {0u, 0u, 0u, 0u};
  for (int i = blockIdx.x * blockDim.x + threadIdx.x; i < n4; i += gridDim.x * blockDim.x)
    p[i] = z;
  if (blockIdx.x == 0 && threadIdx.x < BATCH) ws[OFF_BSUMS + threadIdx.x] = 0u;
}

// One thread per 2 consecutive pixels (float2 = 8 B/lane, perfectly coalesced
// 512 B/wave-request). 625 blocks -> 2-3 waves/SIMD so TLP covers VMEM issue
// gaps (round-3 showed 313 blocks @1.2 waves/SIMD capped at ~3 TB/s delivered
// regardless of MLP depth). Plain loads (no NT: reference 6.3 TB/s copy and
// 4.9 TB/s read-streams use plain loads). Static two-bank pipeline, ~90 VGPR;
// __launch_bounds__(256,2) keeps the allocator from rolling it to 2-deep.
__global__ __launch_bounds__(256, 2) void pixel_stats_kernel(
    const float* __restrict__ A, const float* __restrict__ B,
    unsigned int* __restrict__ keys, float* __restrict__ contrib,
    unsigned int* __restrict__ ws) {
  int tid = blockIdx.x * blockDim.x + threadIdx.x;
  if (tid >= BATCH * HW2) return;
  int b = tid / HW2;
  int p2 = tid - b * HW2;
  const v2f* a  = (const v2f*)(A + (size_t)b * CCH * HW) + p2;
  const v2f* bb = (const v2f*)(B + (size_t)b * CCH * HW) + p2;

  float sa[2] = {0, 0}, ssa[2] = {0, 0};
  float sb[2] = {0, 0}, ssb[2] = {0, 0}, dab[2] = {0, 0};

  v2f xA[8], yA[8], xB[8], yB[8];
#pragma unroll
  for (int k = 0; k < 8; ++k) {
    xA[k] = a[(size_t)k * HW2];
    yA[k] = bb[(size_t)k * HW2];
  }

#pragma unroll 1
  for (int it = 0; it < 16; ++it) {
    const size_t cb = (size_t)it * 16;
#pragma unroll
    for (int k = 0; k < 8; ++k) {
      xB[k] = a[(cb + 8 + (size_t)k) * HW2];
      yB[k] = bb[(cb + 8 + (size_t)k) * HW2];
    }
#pragma unroll
    for (int k = 0; k < 8; ++k) {
#pragma unroll
      for (int j = 0; j < 2; ++j) {
        float xs = xA[k][j], ys = yA[k][j];
        sa[j] += xs;  ssa[j] = fmaf(xs, xs, ssa[j]);
        sb[j] += ys;  ssb[j] = fmaf(ys, ys, ssb[j]);
        dab[j] = fmaf(xs, ys, dab[j]);
      }
    }
    if (it < 15) {
#pragma unroll
      for (int k = 0; k < 8; ++k) {
        xA[k] = a[(cb + 16 + (size_t)k) * HW2];
        yA[k] = bb[(cb + 16 + (size_t)k) * HW2];
      }
    }
#pragma unroll
    for (int k = 0; k < 8; ++k) {
#pragma unroll
      for (int j = 0; j < 2; ++j) {
        float xs = xB[k][j], ys = yB[k][j];
        sa[j] += xs;  ssa[j] = fmaf(xs, xs, ssa[j]);
        sb[j] += ys;  ssb[j] = fmaf(ys, ys, ssb[j]);
        dab[j] = fmaf(xs, ys, dab[j]);
      }
    }
  }

  unsigned int kv[2];
  float cov[2];
  const float invC = 1.0f / (float)CCH;
#pragma unroll
  for (int j = 0; j < 2; ++j) {
    kv[j] = mono_key(ssa[j]);  // score = raw sum of squares
    float mua = sa[j] * invC, mub = sb[j] * invC;
    float cssa = fmaxf(ssa[j] - (float)CCH * mua * mua, 0.f);
    float cssb = fmaxf(ssb[j] - (float)CCH * mub * mub, 0.f);
    float cdot = dab[j] - (float)CCH * mua * mub;
    float siga = sqrtf(cssa / (float)(CCH - 1)) + EPS_LN;
    float sigb = sqrtf(cssb / (float)(CCH - 1)) + EPS_LN;
    float num = cdot / (siga * sigb);
    float na = sqrtf(cssa) / siga;
    float nb = sqrtf(cssb) / sigb;
    cov[j] = 1.0f - num / (fmaxf(na, EPS_COS) * fmaxf(nb, EPS_COS));
  }
  int out = b * HW + p2 * 2;
  *(uint2*)(keys + out)  = make_uint2(kv[0], kv[1]);
  *(v2f*)(contrib + out) = (v2f){cov[0], cov[1]};

  unsigned int* h1 = ws + OFF_HIST1 + (b << 16);
#pragma unroll
  for (int j = 0; j < 2; ++j)
    atomicAdd(&h1[kv[j] >> 16], 1u);
}

// One block per batch (8 x 1024). Pass 0 selects the top-16-bit prefix from
// the global hist1. Then ONE combined sweep over keys: contribs with
// top16 > prefix are summed directly; members of the threshold bin (typically
// a few hundred) are compacted into LDS. The remaining 16 bits are refined
// 8+8 entirely in LDS — no further global passes. Fallback to the proven
// global 8+8 refine if the bin overflows CAP (can't happen for this data,
// kept for correctness).
__global__ __launch_bounds__(1024) void select_sum_kernel(
    const unsigned int* __restrict__ keys, const float* __restrict__ contrib,
    unsigned int* __restrict__ ws) {
  int b = blockIdx.x;
  int t = threadIdx.x;
  const unsigned int* kb = keys + b * HW;
  const float* cbp = contrib + b * HW;

  __shared__ unsigned int suf[1024];
  __shared__ unsigned int bins[64];
  __shared__ unsigned int hbin[256];
  __shared__ unsigned int s_idx, s_above, s_tie, s_cnt;
  __shared__ unsigned int lds_k[CAP];
  __shared__ float lds_c[CAP];

  unsigned int prefix, K;

  // ---- pass 0: global hist1 (65536 bins), K = KSEL -> prefix16, K remaining ----
  {
    const unsigned int* h = ws + OFF_HIST1 + (b << 16);
    unsigned int sum = 0;
#pragma unroll 8
    for (int i = 0; i < 64; ++i) sum += h[t * 64 + i];
    suf[t] = sum;
    __syncthreads();
    for (int off = 1; off < 1024; off <<= 1) {
      unsigned int v = (t + off < 1024) ? suf[t + off] : 0u;
      __syncthreads();
      suf[t] += v;
      __syncthreads();
    }
    unsigned int above = (t == 1023) ? 0u : suf[t + 1];
    if (suf[t] >= (unsigned)KSEL && above < (unsigned)KSEL) { s_idx = (unsigned)t; s_above = above; }
    __syncthreads();
    if (t < 64) bins[t] = h[s_idx * 64 + t];
    __syncthreads();
    if (t == 0) {
      unsigned int cum = s_above;
      int d = 63;
      for (; d >= 0; --d) {
        if (cum + bins[d] >= (unsigned)KSEL) break;
        cum += bins[d];
      }
      s_idx = s_idx * 64 + (unsigned)d;
      s_above = cum;
    }
    __syncthreads();
    prefix = s_idx;                       // top-16-bit prefix of threshold
    K = (unsigned)KSEL - s_above;         // how many to take inside that bin
    __syncthreads();
  }

  // ---- combined sweep: sum contribs above the bin; compact bin members ----
  if (t == 0) s_cnt = 0u;
  __syncthreads();
  float partial = 0.f;
  for (int i = t; i < HW; i += 1024) {
    unsigned int key = kb[i];
    unsigned int h16 = key >> 16;
    if (h16 > prefix) {
      partial += cbp[i];
    } else if (h16 == prefix) {
      unsigned int c = atomicAdd(&s_cnt, 1u);
      if (c < CAP) { lds_k[c] = key & 0xFFFFu; lds_c[c] = cbp[i]; }
    }
  }
  __syncthreads();
  const unsigned int M = s_cnt;

  if (M <= CAP) {
    // ---- in-LDS 8+8-bit refine over the M bin members ----
    // pass 1: bits[15:8]
    if (t < 256) hbin[t] = 0u;
    __syncthreads();
    for (int i = t; i < (int)M; i += 1024) atomicAdd(&hbin[lds_k[i] >> 8], 1u);
    __syncthreads();
    if (t < 256) suf[t] = hbin[t];
    __syncthreads();
    for (int off = 1; off < 256; off <<= 1) {
      unsigned int v = (t < 256 && t + off < 256) ? suf[t + off] : 0u;
      __syncthreads();
      if (t < 256) suf[t] += v;
      __syncthreads();
    }
    if (t < 256) {
      unsigned int above = (t == 255) ? 0u : suf[t + 1];
      if (suf[t] >= K && above < K) { s_idx = (unsigned)t; s_above = above; }
    }
    __syncthreads();
    const unsigned int byte1 = s_idx;
    K -= s_above;
    __syncthreads();
    // pass 2: bits[7:0] among members with bits[15:8]==byte1
    if (t < 256) hbin[t] = 0u;
    __syncthreads();
    for (int i = t; i < (int)M; i += 1024) {
      unsigned int lk = lds_k[i];
      if ((lk >> 8) == byte1) atomicAdd(&hbin[lk & 0xFFu], 1u);
    }
    __syncthreads();
    if (t < 256) suf[t] = hbin[t];
    __syncthreads();
    for (int off = 1; off < 256; off <<= 1) {
      unsigned int v = (t < 256 && t + off < 256) ? suf[t + off] : 0u;
      __syncthreads();
      if (t < 256) suf[t] += v;
      __syncthreads();
    }
    if (t < 256) {
      unsigned int above = (t == 255) ? 0u : suf[t + 1];
      if (suf[t] >= K && above < K) { s_idx = (unsigned)t; s_above = above; }
    }
    __syncthreads();
    const unsigned int Tlow = (byte1 << 8) | s_idx;
    const unsigned int rem = K - s_above;
    if (t == 0) s_tie = 0u;
    __syncthreads();
    for (int i = t; i < (int)M; i += 1024) {
      unsigned int lk = lds_k[i];
      if (lk > Tlow) {
        partial += lds_c[i];
      } else if (lk == Tlow) {
        unsigned int old = atomicAdd(&s_tie, 1u);
        if (old < rem) partial += lds_c[i];
      }
    }
  } else {
    // ---- fallback: global 8+8-bit refine + full tie-sum pass (R3 path) ----
    partial = 0.f;
#pragma unroll 1
    for (int pass = 0; pass < 2; ++pass) {
      if (t < 256) hbin[t] = 0u;
      __syncthreads();
      if (pass == 0) {
        for (int i = t; i < HW; i += 1024) {
          unsigned int key = kb[i];
          if ((key >> 16) == prefix) atomicAdd(&hbin[(key >> 8) & 0xFFu], 1u);
        }
      } else {
        for (int i = t; i < HW; i += 1024) {
          unsigned int key = kb[i];
          if ((key >> 8) == prefix) atomicAdd(&hbin[key & 0xFFu], 1u);
        }
      }
      __syncthreads();
      if (t < 256) suf[t] = hbin[t];
      __syncthreads();
      for (int off = 1; off < 256; off <<= 1) {
        unsigned int v = (t < 256 && t + off < 256) ? suf[t + off] : 0u;
        __syncthreads();
        if (t < 256) suf[t] += v;
        __syncthreads();
      }
      if (t < 256) {
        unsigned int above = (t == 255) ? 0u : suf[t + 1];
        if (suf[t] >= K && above < K) { s_idx = (unsigned)t; s_above = above; }
      }
      __syncthreads();
      prefix = (prefix << 8) | s_idx;
      K = K - s_above;
      __syncthreads();
    }
    const unsigned int T = prefix;
    const unsigned int rem2 = K;
    if (t == 0) s_tie = 0u;
    __syncthreads();
    for (int i = t; i < HW; i += 1024) {
      unsigned int key = kb[i];
      if (key > T) {
        partial += cbp[i];
      } else if (key == T) {
        unsigned int old = atomicAdd(&s_tie, 1u);
        if (old < rem2) partial += cbp[i];
      }
    }
  }

  __syncthreads();
  float* redf = (float*)suf;
  redf[t] = partial;
  __syncthreads();
  for (int off = 512; off > 0; off >>= 1) {
    if (t < off) redf[t] += redf[t + off];
    __syncthreads();
  }
  if (t == 0) ((float*)(ws + OFF_BSUMS))[b] = redf[0];
}

__global__ void finalize_kernel(const unsigned int* __restrict__ ws,
                                const float* __restrict__ dx,
                                const float* __restrict__ dy,
                                const float* __restrict__ dth,
                                float* __restrict__ out) {
  if (threadIdx.x == 0 && blockIdx.x == 0) {
    const float* bsums = (const float*)(ws + OFF_BSUMS);
    float s = 0.f;
    for (int b = 0; b < BATCH; ++b) s += bsums[b];
    float align = s / (float)(BATCH * KSEL);
    float r1 = 0.f, r2 = 0.f;
    for (int b = 0; b < BATCH; ++b) {
      r1 += dx[b] * dx[b] + dy[b] * dy[b];
      r2 += dth[b] * dth[b];
    }
    out[0] = align + 0.1f * (r1 / (float)BATCH + r2 / (float)BATCH);
  }
}

extern "C" void kernel_launch(void* const* d_in, const int* in_sizes, int n_in,
                              void* d_out, int out_size, void* d_ws, size_t ws_size,
                              hipStream_t stream) {
  const float* bev   = (const float*)d_in[0];
  const float* prior = (const float*)d_in[1];
  const float* dx    = (const float*)d_in[2];
  const float* dy    = (const float*)d_in[3];
  const float* dth   = (const float*)d_in[4];
  float* out = (float*)d_out;

  unsigned int* ws = (unsigned int*)d_ws;
  unsigned int* keys = ws + OFF_KEYS;
  float* contrib     = (float*)ws + OFF_CONTRIB;

  zero_kernel<<<256, 256, 0, stream>>>(ws);
  pixel_stats_kernel<<<(BATCH * HW2 + 255) / 256, 256, 0, stream>>>(bev, prior, keys, contrib, ws);
  select_sum_kernel<<<BATCH, 1024, 0, stream>>>(keys, contrib, ws);
  finalize_kernel<<<1, 64, 0, stream>>>(ws, dx, dy, dth, out);
}